// Round 8
// baseline (305.022 us; speedup 1.0000x reference)
//
#include <hip/hip_runtime.h>
#include <math.h>

#define NN 4096
#define CC 256
#define HH 8
#define DD 32
#define EE 65536

typedef unsigned short u16;
typedef unsigned int u32;
typedef unsigned long long u64;
typedef unsigned char u8;

typedef float f32x4 __attribute__((ext_vector_type(4)));
typedef __bf16 bf16x8 __attribute__((ext_vector_type(8)));

__device__ __forceinline__ u16 f2b(float f){
  u32 u = __float_as_uint(f);
  return (u16)((u + 0x7FFFu + ((u >> 16) & 1u)) >> 16);
}
__device__ __forceinline__ float b2f(u16 b){
  return __uint_as_float(((u32)b) << 16);
}
__device__ __forceinline__ u32 pk2(float a, float b){
  u32 r; asm("v_cvt_pk_bf16_f32 %0,%1,%2" : "=v"(r) : "v"(a), "v"(b)); return r;
}

// ---------------- graph: degree, CSR ----------------
__global__ __launch_bounds__(256) void k_deg(const int* __restrict__ ei, int* __restrict__ deg){
  int e = blockIdx.x * 256 + threadIdx.x;
  if (e < EE){
    atomicAdd(&deg[ei[e]], 1);
    atomicAdd(&deg[ei[EE + e]], 1);
  }
}

__global__ __launch_bounds__(256) void k_scan(const int* __restrict__ deg, int* __restrict__ rowp,
                                              int* __restrict__ cur){
  __shared__ int part[256];
  int t = threadIdx.x;
  int local[16];
  int s = 0;
  #pragma unroll
  for (int i = 0; i < 16; i++){ local[i] = s; s += deg[t*16 + i]; }
  part[t] = s;
  __syncthreads();
  for (int off = 1; off < 256; off <<= 1){
    int v = (t >= off) ? part[t - off] : 0;
    __syncthreads();
    part[t] += v;
    __syncthreads();
  }
  int excl = (t == 0) ? 0 : part[t - 1];
  #pragma unroll
  for (int i = 0; i < 16; i++){ int v = excl + local[i]; rowp[t*16+i] = v; cur[t*16+i] = v; }
  if (t == 255) rowp[4096] = excl + s;
}

__global__ __launch_bounds__(256) void k_fill(const int* __restrict__ ei, int* __restrict__ cur,
                                              int* __restrict__ col){
  int e = blockIdx.x * 256 + threadIdx.x;
  if (e < EE){
    int r = ei[e], c = ei[EE + e];
    col[atomicAdd(&cur[r], 1)] = c;
    col[atomicAdd(&cur[c], 1)] = r;
  }
}

// ---------------- hidden = x + deg_emb[min(deg,33)] (bf16) ----------------
__global__ __launch_bounds__(256) void k_hidden(const float* __restrict__ x, const float* __restrict__ demb,
                                                const int* __restrict__ deg, u16* __restrict__ hb){
  int i = blockIdx.x * 256 + threadIdx.x;
  int n = i >> 8, c = i & 255;
  int d = deg[n]; if (d > 33) d = 33;
  hb[i] = f2b(x[i] + demb[d * CC + c]);
}

// ---------------- bit-parallel BFS ----------------
__global__ __launch_bounds__(256) void k_b0(u64* __restrict__ B0){
  int i = blockIdx.x * 256 + threadIdx.x;
  int j = i >> 6, w = i & 63;
  B0[i] = (w == (j >> 6)) ? (1ull << (j & 63)) : 0ull;
}

__global__ __launch_bounds__(256) void k_prop(const u64* __restrict__ Bp, u64* __restrict__ Bn,
                                              const int* __restrict__ rowp, const int* __restrict__ col){
  int i = blockIdx.x * 256 + threadIdx.x;
  int j = i >> 6, w = i & 63;
  u64 acc = Bp[i];
  int s = rowp[j], e = rowp[j + 1];
  u64 a0 = 0, a1 = 0, a2 = 0, a3 = 0;
  int p = s;
  for (; p + 4 <= e; p += 4){
    int c0 = col[p], c1 = col[p+1], c2 = col[p+2], c3 = col[p+3];
    a0 |= Bp[(c0 << 6) + w];
    a1 |= Bp[(c1 << 6) + w];
    a2 |= Bp[(c2 << 6) + w];
    a3 |= Bp[(c3 << 6) + w];
  }
  for (; p < e; p++) a0 |= Bp[(col[p] << 6) + w];
  Bn[i] = acc | (a0 | a1) | (a2 | a3);
}

__global__ __launch_bounds__(256) void k_dist(const u64* __restrict__ B1, const u64* __restrict__ B2,
                                              const u64* __restrict__ B3, const u64* __restrict__ B4,
                                              u8* __restrict__ dist){
  int i = blockIdx.x * 256 + threadIdx.x;
  int j = i >> 6, w = i & 63;
  u64 b1 = B1[i], b2 = B2[i], b3 = B3[i], b4 = B4[i];
  u32 ob[16];
  #pragma unroll
  for (int g = 0; g < 16; g++){
    u32 word = 0;
    #pragma unroll
    for (int q = 0; q < 4; q++){
      int bit = g * 4 + q;
      u32 d;
      if ((b1 >> bit) & 1) d = 1;
      else if ((b2 >> bit) & 1) d = 2;
      else if ((b3 >> bit) & 1) d = 3;
      else if ((b4 >> bit) & 1) d = 4;
      else d = 5;
      if ((w << 6) + bit == j) d = 0;
      word |= d << (q * 8);
    }
    ob[g] = word;
  }
  uint4* dp = (uint4*)(dist + ((size_t)j << 12) + (w << 6));
  uint4* ov = (uint4*)ob;
  dp[0] = ov[0]; dp[1] = ov[1]; dp[2] = ov[2]; dp[3] = ov[3];
}

// ---------------- weight transpose+convert: fp32 [K][N] -> bf16 [N][K], coalesced ----------------
__global__ __launch_bounds__(256) void k_tconv(const float* __restrict__ W0, const float* __restrict__ W1,
                                               const float* __restrict__ W2, const float* __restrict__ W3,
                                               const float* __restrict__ W4, const float* __restrict__ W5,
                                               u16* __restrict__ T0, u16* __restrict__ T1,
                                               u16* __restrict__ T2, u16* __restrict__ T3,
                                               u16* __restrict__ T4, u16* __restrict__ T5){
  __shared__ float Ts[64][65];
  int z = blockIdx.z;
  const float* W; u16* T; int K, N;
  switch (z){
    case 0: W = W0; T = T0; K = 256; N = 256; break;
    case 1: W = W1; T = T1; K = 256; N = 256; break;
    case 2: W = W2; T = T2; K = 256; N = 256; break;
    case 3: W = W3; T = T3; K = 256; N = 256; break;
    case 4: W = W4; T = T4; K = 256; N = 512; break;
    default: W = W5; T = T5; K = 512; N = 256; break;
  }
  int n0 = blockIdx.x * 64, k0 = blockIdx.y * 64;
  if (n0 >= N || k0 >= K) return;
  int t = threadIdx.x;
  int r = t >> 4, c4 = (t & 15) * 4;
  #pragma unroll
  for (int it = 0; it < 4; it++){
    float4 v = *(const float4*)&W[(size_t)(k0 + it*16 + r) * N + n0 + c4];
    Ts[it*16 + r][c4+0] = v.x; Ts[it*16 + r][c4+1] = v.y;
    Ts[it*16 + r][c4+2] = v.z; Ts[it*16 + r][c4+3] = v.w;
  }
  __syncthreads();
  #pragma unroll
  for (int it = 0; it < 4; it++){
    int n = it*16 + r;
    uint2 o;
    o.x = pk2(Ts[c4+0][n], Ts[c4+1][n]);
    o.y = pk2(Ts[c4+2][n], Ts[c4+3][n]);
    *(uint2*)&T[(size_t)(n0 + n) * K + k0 + c4] = o;
  }
}

__global__ __launch_bounds__(256) void k_bcat(const float* __restrict__ a, const float* __restrict__ b,
                                              const float* __restrict__ c, float* __restrict__ o){
  int i = blockIdx.x * 256 + threadIdx.x;
  if (i < 768){
    float v = (i < 256) ? a[i] : (i < 512) ? b[i - 256] : c[i - 512];
    o[i] = v;
  }
}

// ---------------- bf16 MFMA GEMM, 32x64 tile, K-step 64 ----------------
// mode: 1 f32 out; 2 bf16 out; 8 GELU; 16 scale cols<256 by (1/sqrt(32))*log2(e)
__global__ __launch_bounds__(256) void k_gemm32(const u16* __restrict__ A, const u16* __restrict__ Wt,
                                                const float* __restrict__ bias,
                                                float* __restrict__ outF, u16* __restrict__ outB,
                                                u16* __restrict__ outT,
                                                int M, int N, int K, int OS, int mode){
  __shared__ __align__(16) u16 As[32][72];
  __shared__ __align__(16) u16 Bs[64][72];
  int t = threadIdx.x;
  int lane = t & 63;
  int wv = t >> 6;
  int m0 = blockIdx.x * 32, n0 = blockIdx.y * 64;
  int ar = t >> 3, ak = (t & 7) * 8;
  int br = t >> 2, bk = (t & 3) * 16;
  int row16 = lane & 15, kq = (lane >> 4) * 8, rg = (lane >> 4) * 4;
  f32x4 acc0 = {0.f,0.f,0.f,0.f}, acc1 = {0.f,0.f,0.f,0.f};
  for (int k0 = 0; k0 < K; k0 += 64){
    __syncthreads();
    *(bf16x8*)&As[ar][ak]   = *(const bf16x8*)&A [(size_t)(m0 + ar) * K + k0 + ak];
    *(bf16x8*)&Bs[br][bk]   = *(const bf16x8*)&Wt[(size_t)(n0 + br) * K + k0 + bk];
    *(bf16x8*)&Bs[br][bk+8] = *(const bf16x8*)&Wt[(size_t)(n0 + br) * K + k0 + bk + 8];
    __syncthreads();
    #pragma unroll
    for (int ks = 0; ks < 2; ks++){
      bf16x8 a0 = *(const bf16x8*)&As[     row16][ks*32 + kq];
      bf16x8 a1 = *(const bf16x8*)&As[16 + row16][ks*32 + kq];
      bf16x8 b  = *(const bf16x8*)&Bs[wv*16 + row16][ks*32 + kq];
      acc0 = __builtin_amdgcn_mfma_f32_16x16x32_bf16(a0, b, acc0, 0, 0, 0);
      acc1 = __builtin_amdgcn_mfma_f32_16x16x32_bf16(a1, b, acc1, 0, 0, 0);
    }
  }
  int gn = n0 + wv*16 + row16;
  float bv = bias[gn];
  #pragma unroll
  for (int fm = 0; fm < 2; fm++){
    f32x4 aa = fm ? acc1 : acc0;
    #pragma unroll
    for (int r = 0; r < 4; r++){
      int gm = m0 + fm*16 + rg + r;
      float v = aa[r] + bv;
      if (mode & 8) v = 0.5f * v * (1.0f + erff(v * 0.70710678118654752f));
      if ((mode & 16) && gn < 256) v *= 0.25506600600499404f;
      if (outT && gn >= 512)      outT[(size_t)(gn - 512) * M + gm] = f2b(v);
      else if (mode & 1)          outF[(size_t)gm * N + gn] = v;
      else                        outB[(size_t)gm * OS + gn] = f2b(v);
    }
  }
}

// ---------------- flash attention: swapped QK^T, fixed max, v_perm byte-bias, split-K z=8 ----------------
// Shared double-buffered dist staging (dist is head-independent; all 4 waves use the same tile).
// Q pre-scaled by (1/sqrt(32))*log2(e). p = exp2(s + ub/256); uniform offset cancels in o/L.
__global__ __launch_bounds__(256) void k_attn(const u16* __restrict__ qg, const u16* __restrict__ kg,
                                              int CS, const u16* __restrict__ vtg,
                                              const u8* __restrict__ dist,
                                              const float* __restrict__ spa,
                                              u16* __restrict__ pacc, float* __restrict__ pml){
  __shared__ __align__(16) u16 P[4][32][72];     // per-wave [q][k]
  __shared__ __align__(16) u8 dls[2][32][72];    // shared [q][k], double-buffered
  int t = threadIdx.x;
  int lane = t & 63;
  int wv = t >> 6;
  int h = blockIdx.y * 4 + wv;
  int q0 = blockIdx.x * 32;
  int ck = blockIdx.z;
  int kbase = ck * 512;
  int row16 = lane & 15;
  int kq = (lane >> 4) * 8;
  int rg = (lane >> 4) * 4;
  int hDD = h * DD;

  // per-head bias bytes: ub = round((spa*log2e + 0.5)*256), packed for v_perm
  u32 ub[6];
  #pragma unroll
  for (int b = 0; b < 6; b++){
    float f = fmaf(spa[b * 8 + h], 369.32993046f, 128.5f);
    int ui = (int)f;
    ui = ui < 0 ? 0 : (ui > 255 ? 255 : ui);
    ub[b] = (u32)ui;
  }
  u32 B0123 = ub[0] | (ub[1] << 8) | (ub[2] << 16) | (ub[3] << 24);
  u32 B45   = ub[4] | (ub[5] << 8);

  bf16x8 qf0 = *(const bf16x8*)&qg[(size_t)(q0 +      row16) * CS + hDD + kq];
  bf16x8 qf1 = *(const bf16x8*)&qg[(size_t)(q0 + 16 + row16) * CS + hDD + kq];

  // pointer-bumped bases
  const u16* kp0 = kg  + (size_t)(kbase +      row16) * CS + hDD + kq;
  const u16* kp1 = kg  + (size_t)(kbase + 16 + row16) * CS + hDD + kq;
  const u16* kp2 = kg  + (size_t)(kbase + 32 + row16) * CS + hDD + kq;
  const u16* kp3 = kg  + (size_t)(kbase + 48 + row16) * CS + hDD + kq;
  const u16* vp0 = vtg + (size_t)(hDD +      row16) * NN + kbase + kq;
  const u16* vp1 = vtg + (size_t)(hDD + 16 + row16) * NN + kbase + kq;

  // cooperative dist staging: 256 threads cover the 32x64 tile (one uint2 each)
  int drow = t >> 3, dcol = (t & 7) * 8;
  const u8* dp = dist + (size_t)(q0 + drow) * NN + kbase + dcol;
  uint2 dr = *(const uint2*)dp; dp += 64;
  *(uint2*)&dls[0][drow][dcol] = dr;

  f32x4 zero = {0.f, 0.f, 0.f, 0.f};
  f32x4 acc[2][2] = {{zero, zero}, {zero, zero}};
  float ls[2] = {0.f, 0.f};
  __syncthreads();                               // dls[0] ready

  for (int tt = 0; tt < 8; tt++){
    if (tt != 7){ dr = *(const uint2*)dp; dp += 64; }   // prefetch next tile
    const u8 (*dcur)[72] = dls[tt & 1];
    // swapped QK^T
    bf16x8 kf0 = *(const bf16x8*)kp0; kp0 += 64 * 512;
    bf16x8 kf1 = *(const bf16x8*)kp1; kp1 += 64 * 512;
    bf16x8 kf2 = *(const bf16x8*)kp2; kp2 += 64 * 512;
    bf16x8 kf3 = *(const bf16x8*)kp3; kp3 += 64 * 512;
    f32x4 sc[2][4];
    sc[0][0] = __builtin_amdgcn_mfma_f32_16x16x32_bf16(kf0, qf0, zero, 0, 0, 0);
    sc[1][0] = __builtin_amdgcn_mfma_f32_16x16x32_bf16(kf0, qf1, zero, 0, 0, 0);
    sc[0][1] = __builtin_amdgcn_mfma_f32_16x16x32_bf16(kf1, qf0, zero, 0, 0, 0);
    sc[1][1] = __builtin_amdgcn_mfma_f32_16x16x32_bf16(kf1, qf1, zero, 0, 0, 0);
    sc[0][2] = __builtin_amdgcn_mfma_f32_16x16x32_bf16(kf2, qf0, zero, 0, 0, 0);
    sc[1][2] = __builtin_amdgcn_mfma_f32_16x16x32_bf16(kf2, qf1, zero, 0, 0, 0);
    sc[0][3] = __builtin_amdgcn_mfma_f32_16x16x32_bf16(kf3, qf0, zero, 0, 0, 0);
    sc[1][3] = __builtin_amdgcn_mfma_f32_16x16x32_bf16(kf3, qf1, zero, 0, 0, 0);
    // softmax (fixed max): p = exp2(s + ub/256), ub selected by v_perm from dist bytes
    #pragma unroll
    for (int fm = 0; fm < 2; fm++){
      int qrow = fm*16 + row16;
      float rs = 0.f;
      #pragma unroll
      for (int fn = 0; fn < 4; fn++){
        u32 dw = *(const u32*)&dcur[qrow][fn*16 + rg];
        u32 pb = __builtin_amdgcn_perm(B45, B0123, dw);   // 4 bias bytes
        float p0 = exp2f(fmaf((float)( pb        & 255u), 0.00390625f, sc[fm][fn][0]));
        float p1 = exp2f(fmaf((float)((pb >>  8) & 255u), 0.00390625f, sc[fm][fn][1]));
        float p2 = exp2f(fmaf((float)((pb >> 16) & 255u), 0.00390625f, sc[fm][fn][2]));
        float p3 = exp2f(fmaf((float)( pb >> 24        ), 0.00390625f, sc[fm][fn][3]));
        rs += (p0 + p1) + (p2 + p3);
        uint2 pw = { pk2(p0, p1), pk2(p2, p3) };
        *(uint2*)&P[wv][qrow][fn*16 + rg] = pw;
      }
      ls[fm] += rs;
    }
    // PV
    #pragma unroll
    for (int ks = 0; ks < 2; ks++){
      bf16x8 pa0 = *(const bf16x8*)&P[wv][     row16][ks*32 + kq];
      bf16x8 pa1 = *(const bf16x8*)&P[wv][16 + row16][ks*32 + kq];
      bf16x8 vf0 = *(const bf16x8*)(vp0 + ks*32);
      bf16x8 vf1 = *(const bf16x8*)(vp1 + ks*32);
      acc[0][0] = __builtin_amdgcn_mfma_f32_16x16x32_bf16(pa0, vf0, acc[0][0], 0, 0, 0);
      acc[0][1] = __builtin_amdgcn_mfma_f32_16x16x32_bf16(pa0, vf1, acc[0][1], 0, 0, 0);
      acc[1][0] = __builtin_amdgcn_mfma_f32_16x16x32_bf16(pa1, vf0, acc[1][0], 0, 0, 0);
      acc[1][1] = __builtin_amdgcn_mfma_f32_16x16x32_bf16(pa1, vf1, acc[1][1], 0, 0, 0);
    }
    vp0 += 64; vp1 += 64;
    if (tt != 7){
      *(uint2*)&dls[(tt + 1) & 1][drow][dcol] = dr;     // commit next tile
      __syncthreads();
    }
  }
  // reduce l across the 4 lane-groups (disjoint k per group)
  #pragma unroll
  for (int fm = 0; fm < 2; fm++){
    ls[fm] += __shfl_xor(ls[fm], 16, 64);
    ls[fm] += __shfl_xor(ls[fm], 32, 64);
  }
  // write partials (bf16)
  size_t base = ((size_t)ck * 8 + h) * 4096 + q0;
  #pragma unroll
  for (int fm = 0; fm < 2; fm++)
    #pragma unroll
    for (int fd = 0; fd < 2; fd++)
      #pragma unroll
      for (int r = 0; r < 4; r++)
        pacc[(base + fm*16 + rg + r) * 32 + fd*16 + row16] = f2b(acc[fm][fd][r]);
  if ((lane >> 4) == 0){
    #pragma unroll
    for (int fm = 0; fm < 2; fm++)
      pml[base + fm*16 + row16] = ls[fm];
  }
}

// ---------------- split-K merge: plain sums (fixed max) ----------------
__global__ __launch_bounds__(256) void k_merge(const u16* __restrict__ pacc,
                                               const float* __restrict__ pml,
                                               u16* __restrict__ attb){
  int row = blockIdx.x;
  int t = threadIdx.x;
  int h = t >> 5, col = t & 31;
  float o = 0.f, L = 0.f;
  #pragma unroll
  for (int c = 0; c < 8; c++){
    size_t base = ((size_t)c * 8 + h) * 4096 + row;
    o += b2f(pacc[base * 32 + col]);
    L += pml[base];
  }
  attb[(size_t)row * 256 + h * 32 + col] = f2b(o / L);
}

// ---------------- residual + LayerNorm (wave per row) ----------------
__global__ __launch_bounds__(256) void k_ln(const float* __restrict__ ina, const float* __restrict__ inb,
                                            const float* __restrict__ g, const float* __restrict__ b,
                                            float* __restrict__ outF, u16* __restrict__ outB){
  int t = threadIdx.x;
  int wv = t >> 6, lane = t & 63;
  int row = blockIdx.x * 4 + wv;
  size_t base = (size_t)row * CC + lane * 4;
  float4 xa = *(const float4*)&ina[base];
  float4 xb = *(const float4*)&inb[base];
  float v0 = xa.x + xb.x, v1 = xa.y + xb.y, v2 = xa.z + xb.z, v3 = xa.w + xb.w;
  float s  = v0 + v1 + v2 + v3;
  float s2 = v0*v0 + v1*v1 + v2*v2 + v3*v3;
  #pragma unroll
  for (int m = 1; m < 64; m <<= 1){
    s  += __shfl_xor(s,  m, 64);
    s2 += __shfl_xor(s2, m, 64);
  }
  float mu  = s * (1.0f / 256.0f);
  float var = s2 * (1.0f / 256.0f) - mu * mu;
  float rs  = rsqrtf(var + 1e-5f);
  float4 gv = *(const float4*)&g[lane * 4];
  float4 bv = *(const float4*)&b[lane * 4];
  float o0 = (v0 - mu) * rs * gv.x + bv.x;
  float o1 = (v1 - mu) * rs * gv.y + bv.y;
  float o2 = (v2 - mu) * rs * gv.z + bv.z;
  float o3 = (v3 - mu) * rs * gv.w + bv.w;
  if (outF){ float4 o = {o0, o1, o2, o3}; *(float4*)&outF[base] = o; }
  if (outB){
    outB[base+0] = f2b(o0); outB[base+1] = f2b(o1);
    outB[base+2] = f2b(o2); outB[base+3] = f2b(o3);
  }
}

// ---------------- launch ----------------
extern "C" void kernel_launch(void* const* d_in, const int* in_sizes, int n_in,
                              void* d_out, int out_size, void* d_ws, size_t ws_size,
                              hipStream_t stream){
  const float* x    = (const float*)d_in[0];
  const int*   ei   = (const int*)  d_in[1];
  const float* demb = (const float*)d_in[2];
  const float* spa  = (const float*)d_in[3];
  const float* Wq   = (const float*)d_in[4];
  const float* bq   = (const float*)d_in[5];
  const float* Wk   = (const float*)d_in[6];
  const float* bk   = (const float*)d_in[7];
  const float* Wv   = (const float*)d_in[8];
  const float* bv   = (const float*)d_in[9];
  const float* Wo   = (const float*)d_in[10];
  const float* bo   = (const float*)d_in[11];
  const float* g1   = (const float*)d_in[12];
  const float* b1   = (const float*)d_in[13];
  const float* g2   = (const float*)d_in[14];
  const float* b2   = (const float*)d_in[15];
  const float* Wf1  = (const float*)d_in[16];
  const float* bf1  = (const float*)d_in[17];
  const float* Wf2  = (const float*)d_in[18];
  const float* bf2  = (const float*)d_in[19];

  char* ws = (char*)d_ws;
  size_t off = 0;
  auto take = [&](size_t bytes)->char*{
    char* p = ws + off;
    off = (off + bytes + 255) & ~(size_t)255;
    return p;
  };
  int* deg    = (int*)take(4096 * 4);
  int* rowp   = (int*)take(4097 * 4);
  int* cur    = (int*)take(4096 * 4);
  int* col    = (int*)take(131072 * 4);
  u16* hid    = (u16*)take(2097152);
  u16* Wqkvt  = (u16*)take(768 * 256 * 2);
  u16* Wot    = (u16*)take(131072);
  u16* Wf1t   = (u16*)take(262144);
  u16* Wf2t   = (u16*)take(262144);
  float* bcat = (float*)take(768 * 4);
  u16* qkv    = (u16*)take(4194304);        // [4096][512] Q|K bf16 (Q pre-scaled)
  u16* vt     = (u16*)take(2097152);        // [256][4096] V transposed
  u16* attb   = (u16*)take(2097152);
  char* SC    = take(18 * 1048576);         // BFS / attn partials / post-attn scratch
  u8* dist    = (u8*)take(16777216);
  u64* B[5];
  for (int i = 0; i < 5; i++) B[i] = (u64*)(SC + (size_t)i * 2097152);
  u16*   pacc    = (u16*)SC;                         // 16 MB bf16 partials (B dead after k_dist)
  float* pml     = (float*)(SC + 16777216);          // 1 MB
  float* attnout = (float*)SC;                       // 4 MB (pacc dead after merge)
  float* hf      = (float*)(SC + 4194304);           // 4 MB
  u16*   hbf     = (u16*)  (SC + 8388608);           // 2 MB
  u16*   ff1     = (u16*)  dist;                     // 4 MB (dist dead after attn)
  float* ff2     = (float*)(dist + 8388608);         // 4 MB
  float* outp    = (float*)d_out;

  hipMemsetAsync(deg, 0, 4096 * 4, stream);
  k_deg   <<<256,  256, 0, stream>>>(ei, deg);
  k_scan  <<<1,    256, 0, stream>>>(deg, rowp, cur);
  k_fill  <<<256,  256, 0, stream>>>(ei, cur, col);
  k_hidden<<<4096, 256, 0, stream>>>(x, demb, deg, hid);
  k_b0    <<<1024, 256, 0, stream>>>(B[0]);
  for (int d = 0; d < 4; d++)
    k_prop<<<1024, 256, 0, stream>>>(B[d], B[d + 1], rowp, col);
  k_dist  <<<1024, 256, 0, stream>>>(B[1], B[2], B[3], B[4], dist);

  k_tconv<<<dim3(8, 8, 6), 256, 0, stream>>>(Wq, Wk, Wv, Wo, Wf1, Wf2,
                                             Wqkvt, Wqkvt + 256*256, Wqkvt + 512*256,
                                             Wot, Wf1t, Wf2t);
  k_bcat <<<3, 256, 0, stream>>>(bq, bk, bv, bcat);

  // fused QKV: N=768; cols [0,512) -> qkv row-major (Q pre-scaled), cols [512,768) -> vt transposed
  k_gemm32<<<dim3(128, 12), 256, 0, stream>>>(hid, Wqkvt, bcat, nullptr, qkv, vt,
                                              4096, 768, 256, 512, 2 | 16);

  k_attn <<<dim3(128, 2, 8), 256, 0, stream>>>(qkv, qkv + 256, 512, vt, dist, spa, pacc, pml);
  k_merge<<<4096, 256, 0, stream>>>(pacc, pml, attb);

  k_gemm32<<<dim3(128, 4), 256, 0, stream>>>(attb, Wot, bo, attnout, nullptr, nullptr,
                                             4096, 256, 256, 256, 1);
  k_ln   <<<1024, 256, 0, stream>>>(x, attnout, g1, b1, hf, hbf);
  k_gemm32<<<dim3(128, 8), 256, 0, stream>>>(hbf, Wf1t, bf1, nullptr, ff1, nullptr,
                                             4096, 512, 256, 512, 2 | 8);
  k_gemm32<<<dim3(128, 4), 256, 0, stream>>>(ff1, Wf2t, bf2, ff2, nullptr, nullptr,
                                             4096, 256, 512, 256, 1);
  k_ln   <<<1024, 256, 0, stream>>>(hf, ff2, g2, b2, outp, nullptr);
}

// Round 9
// 300.782 us; speedup vs baseline: 1.0141x; 1.0141x over previous
//
#include <hip/hip_runtime.h>
#include <math.h>

#define NN 4096
#define CC 256
#define HH 8
#define DD 32
#define EE 65536

typedef unsigned short u16;
typedef unsigned int u32;
typedef unsigned long long u64;
typedef unsigned char u8;

typedef float f32x4 __attribute__((ext_vector_type(4)));
typedef __bf16 bf16x8 __attribute__((ext_vector_type(8)));

__device__ __forceinline__ u16 f2b(float f){
  u32 u = __float_as_uint(f);
  return (u16)((u + 0x7FFFu + ((u >> 16) & 1u)) >> 16);
}
__device__ __forceinline__ float b2f(u16 b){
  return __uint_as_float(((u32)b) << 16);
}
__device__ __forceinline__ u32 pk2(float a, float b){
  u32 r; asm("v_cvt_pk_bf16_f32 %0,%1,%2" : "=v"(r) : "v"(a), "v"(b)); return r;
}

// ---------------- graph: degree, CSR ----------------
__global__ __launch_bounds__(256) void k_deg(const int* __restrict__ ei, int* __restrict__ deg){
  int e = blockIdx.x * 256 + threadIdx.x;
  if (e < EE){
    atomicAdd(&deg[ei[e]], 1);
    atomicAdd(&deg[ei[EE + e]], 1);
  }
}

__global__ __launch_bounds__(256) void k_scan(const int* __restrict__ deg, int* __restrict__ rowp,
                                              int* __restrict__ cur){
  __shared__ int part[256];
  int t = threadIdx.x;
  int local[16];
  int s = 0;
  #pragma unroll
  for (int i = 0; i < 16; i++){ local[i] = s; s += deg[t*16 + i]; }
  part[t] = s;
  __syncthreads();
  for (int off = 1; off < 256; off <<= 1){
    int v = (t >= off) ? part[t - off] : 0;
    __syncthreads();
    part[t] += v;
    __syncthreads();
  }
  int excl = (t == 0) ? 0 : part[t - 1];
  #pragma unroll
  for (int i = 0; i < 16; i++){ int v = excl + local[i]; rowp[t*16+i] = v; cur[t*16+i] = v; }
  if (t == 255) rowp[4096] = excl + s;
}

__global__ __launch_bounds__(256) void k_fill(const int* __restrict__ ei, int* __restrict__ cur,
                                              int* __restrict__ col){
  int e = blockIdx.x * 256 + threadIdx.x;
  if (e < EE){
    int r = ei[e], c = ei[EE + e];
    col[atomicAdd(&cur[r], 1)] = c;
    col[atomicAdd(&cur[c], 1)] = r;
  }
}

// ---------------- hidden = x + deg_emb[min(deg,33)] (bf16) ----------------
__global__ __launch_bounds__(256) void k_hidden(const float* __restrict__ x, const float* __restrict__ demb,
                                                const int* __restrict__ deg, u16* __restrict__ hb){
  int i = blockIdx.x * 256 + threadIdx.x;
  int n = i >> 8, c = i & 255;
  int d = deg[n]; if (d > 33) d = 33;
  hb[i] = f2b(x[i] + demb[d * CC + c]);
}

// ---------------- bit-parallel BFS ----------------
__global__ __launch_bounds__(256) void k_b0(u64* __restrict__ B0){
  int i = blockIdx.x * 256 + threadIdx.x;
  int j = i >> 6, w = i & 63;
  B0[i] = (w == (j >> 6)) ? (1ull << (j & 63)) : 0ull;
}

__global__ __launch_bounds__(256) void k_prop(const u64* __restrict__ Bp, u64* __restrict__ Bn,
                                              const int* __restrict__ rowp, const int* __restrict__ col){
  int i = blockIdx.x * 256 + threadIdx.x;
  int j = i >> 6, w = i & 63;
  u64 acc = Bp[i];
  int s = rowp[j], e = rowp[j + 1];
  u64 a0 = 0, a1 = 0, a2 = 0, a3 = 0;
  int p = s;
  for (; p + 4 <= e; p += 4){
    int c0 = col[p], c1 = col[p+1], c2 = col[p+2], c3 = col[p+3];
    a0 |= Bp[(c0 << 6) + w];
    a1 |= Bp[(c1 << 6) + w];
    a2 |= Bp[(c2 << 6) + w];
    a3 |= Bp[(c3 << 6) + w];
  }
  for (; p < e; p++) a0 |= Bp[(col[p] << 6) + w];
  Bn[i] = acc | (a0 | a1) | (a2 | a3);
}

__global__ __launch_bounds__(256) void k_dist(const u64* __restrict__ B1, const u64* __restrict__ B2,
                                              const u64* __restrict__ B3, const u64* __restrict__ B4,
                                              u8* __restrict__ dist){
  int i = blockIdx.x * 256 + threadIdx.x;
  int j = i >> 6, w = i & 63;
  u64 b1 = B1[i], b2 = B2[i], b3 = B3[i], b4 = B4[i];
  u32 ob[16];
  #pragma unroll
  for (int g = 0; g < 16; g++){
    u32 word = 0;
    #pragma unroll
    for (int q = 0; q < 4; q++){
      int bit = g * 4 + q;
      u32 d;
      if ((b1 >> bit) & 1) d = 1;
      else if ((b2 >> bit) & 1) d = 2;
      else if ((b3 >> bit) & 1) d = 3;
      else if ((b4 >> bit) & 1) d = 4;
      else d = 5;
      if ((w << 6) + bit == j) d = 0;
      word |= d << (q * 8);
    }
    ob[g] = word;
  }
  uint4* dp = (uint4*)(dist + ((size_t)j << 12) + (w << 6));
  uint4* ov = (uint4*)ob;
  dp[0] = ov[0]; dp[1] = ov[1]; dp[2] = ov[2]; dp[3] = ov[3];
}

// ---------------- weight transpose+convert: fp32 [K][N] -> bf16 [N][K], coalesced ----------------
__global__ __launch_bounds__(256) void k_tconv(const float* __restrict__ W0, const float* __restrict__ W1,
                                               const float* __restrict__ W2, const float* __restrict__ W3,
                                               const float* __restrict__ W4, const float* __restrict__ W5,
                                               u16* __restrict__ T0, u16* __restrict__ T1,
                                               u16* __restrict__ T2, u16* __restrict__ T3,
                                               u16* __restrict__ T4, u16* __restrict__ T5){
  __shared__ float Ts[64][65];
  int z = blockIdx.z;
  const float* W; u16* T; int K, N;
  switch (z){
    case 0: W = W0; T = T0; K = 256; N = 256; break;
    case 1: W = W1; T = T1; K = 256; N = 256; break;
    case 2: W = W2; T = T2; K = 256; N = 256; break;
    case 3: W = W3; T = T3; K = 256; N = 256; break;
    case 4: W = W4; T = T4; K = 256; N = 512; break;
    default: W = W5; T = T5; K = 512; N = 256; break;
  }
  int n0 = blockIdx.x * 64, k0 = blockIdx.y * 64;
  if (n0 >= N || k0 >= K) return;
  int t = threadIdx.x;
  int r = t >> 4, c4 = (t & 15) * 4;
  #pragma unroll
  for (int it = 0; it < 4; it++){
    float4 v = *(const float4*)&W[(size_t)(k0 + it*16 + r) * N + n0 + c4];
    Ts[it*16 + r][c4+0] = v.x; Ts[it*16 + r][c4+1] = v.y;
    Ts[it*16 + r][c4+2] = v.z; Ts[it*16 + r][c4+3] = v.w;
  }
  __syncthreads();
  #pragma unroll
  for (int it = 0; it < 4; it++){
    int n = it*16 + r;
    uint2 o;
    o.x = pk2(Ts[c4+0][n], Ts[c4+1][n]);
    o.y = pk2(Ts[c4+2][n], Ts[c4+3][n]);
    *(uint2*)&T[(size_t)(n0 + n) * K + k0 + c4] = o;
  }
}

__global__ __launch_bounds__(256) void k_bcat(const float* __restrict__ a, const float* __restrict__ b,
                                              const float* __restrict__ c, float* __restrict__ o){
  int i = blockIdx.x * 256 + threadIdx.x;
  if (i < 768){
    float v = (i < 256) ? a[i] : (i < 512) ? b[i - 256] : c[i - 512];
    o[i] = v;
  }
}

// ---------------- bf16 MFMA GEMM, 32x64 tile, K-step 64 ----------------
// mode: 1 f32 out; 2 bf16 out; 8 GELU; 16 scale cols<256 by (1/sqrt(32))*log2(e)
__global__ __launch_bounds__(256) void k_gemm32(const u16* __restrict__ A, const u16* __restrict__ Wt,
                                                const float* __restrict__ bias,
                                                float* __restrict__ outF, u16* __restrict__ outB,
                                                u16* __restrict__ outT,
                                                int M, int N, int K, int OS, int mode){
  __shared__ __align__(16) u16 As[32][72];
  __shared__ __align__(16) u16 Bs[64][72];
  int t = threadIdx.x;
  int lane = t & 63;
  int wv = t >> 6;
  int m0 = blockIdx.x * 32, n0 = blockIdx.y * 64;
  int ar = t >> 3, ak = (t & 7) * 8;
  int br = t >> 2, bk = (t & 3) * 16;
  int row16 = lane & 15, kq = (lane >> 4) * 8, rg = (lane >> 4) * 4;
  f32x4 acc0 = {0.f,0.f,0.f,0.f}, acc1 = {0.f,0.f,0.f,0.f};
  for (int k0 = 0; k0 < K; k0 += 64){
    __syncthreads();
    *(bf16x8*)&As[ar][ak]   = *(const bf16x8*)&A [(size_t)(m0 + ar) * K + k0 + ak];
    *(bf16x8*)&Bs[br][bk]   = *(const bf16x8*)&Wt[(size_t)(n0 + br) * K + k0 + bk];
    *(bf16x8*)&Bs[br][bk+8] = *(const bf16x8*)&Wt[(size_t)(n0 + br) * K + k0 + bk + 8];
    __syncthreads();
    #pragma unroll
    for (int ks = 0; ks < 2; ks++){
      bf16x8 a0 = *(const bf16x8*)&As[     row16][ks*32 + kq];
      bf16x8 a1 = *(const bf16x8*)&As[16 + row16][ks*32 + kq];
      bf16x8 b  = *(const bf16x8*)&Bs[wv*16 + row16][ks*32 + kq];
      acc0 = __builtin_amdgcn_mfma_f32_16x16x32_bf16(a0, b, acc0, 0, 0, 0);
      acc1 = __builtin_amdgcn_mfma_f32_16x16x32_bf16(a1, b, acc1, 0, 0, 0);
    }
  }
  int gn = n0 + wv*16 + row16;
  float bv = bias[gn];
  #pragma unroll
  for (int fm = 0; fm < 2; fm++){
    f32x4 aa = fm ? acc1 : acc0;
    #pragma unroll
    for (int r = 0; r < 4; r++){
      int gm = m0 + fm*16 + rg + r;
      float v = aa[r] + bv;
      if (mode & 8) v = 0.5f * v * (1.0f + erff(v * 0.70710678118654752f));
      if ((mode & 16) && gn < 256) v *= 0.25506600600499404f;
      if (outT && gn >= 512)      outT[(size_t)(gn - 512) * M + gm] = f2b(v);
      else if (mode & 1)          outF[(size_t)gm * N + gn] = v;
      else                        outB[(size_t)gm * OS + gn] = f2b(v);
    }
  }
}

// ---------------- flash attention: swapped QK^T, fixed max, v_perm byte-bias, split-K z=8 ----------------
// VGPR <= 64 target: u32-offset addressing, per-fn fused softmax, fd-outer PV.
// Q pre-scaled by (1/sqrt(32))*log2(e). p = exp2(s + ub/256); uniform offset cancels in o/L.
__global__ __launch_bounds__(256, 8) void k_attn(const u16* __restrict__ qg, const u16* __restrict__ kg,
                                                 const u16* __restrict__ vtg,
                                                 const u8* __restrict__ dist,
                                                 const float* __restrict__ spa,
                                                 u16* __restrict__ pacc, float* __restrict__ pml){
  __shared__ __align__(16) u16 P[4][32][72];     // per-wave [q][k]
  __shared__ __align__(16) u8 dls[4][32][72];    // per-wave [q][k]
  int t = threadIdx.x;
  int lane = t & 63;
  int wv = t >> 6;
  int h = blockIdx.y * 4 + wv;
  int q0 = blockIdx.x * 32;
  int ck = blockIdx.z;
  int kbase = ck * 512;
  int row16 = lane & 15;
  int kq = (lane >> 4) * 8;
  int rg = (lane >> 4) * 4;
  int hDD = h * DD;

  // per-head bias bytes: ub = round((spa*log2e + 0.5)*256), packed for v_perm
  u32 B0123, B45;
  {
    u32 ub[6];
    #pragma unroll
    for (int b = 0; b < 6; b++){
      float f = fmaf(spa[b * 8 + h], 369.32993046f, 128.5f);
      int ui = (int)f;
      ui = ui < 0 ? 0 : (ui > 255 ? 255 : ui);
      ub[b] = (u32)ui;
    }
    B0123 = ub[0] | (ub[1] << 8) | (ub[2] << 16) | (ub[3] << 24);
    B45   = ub[4] | (ub[5] << 8);
  }

  bf16x8 qf0 = *(const bf16x8*)&qg[(u32)(q0 +      row16) * 512u + hDD + kq];
  bf16x8 qf1 = *(const bf16x8*)&qg[(u32)(q0 + 16 + row16) * 512u + hDD + kq];

  // 32-bit element offsets (SGPR base + voffset form)
  u32 koff  = (u32)(kbase + row16) * 512u + hDD + kq;
  u32 voff0 = (u32)(hDD +      row16) * 4096u + kbase + kq;
  u32 voff1 = (u32)(hDD + 16 + row16) * 4096u + kbase + kq;
  int srow = lane >> 3, scol = (lane & 7) * 8;
  u32 doff = (u32)(q0 + srow) * 4096u + kbase + scol;

  f32x4 zero = {0.f, 0.f, 0.f, 0.f};
  f32x4 acc00 = zero, acc01 = zero, acc10 = zero, acc11 = zero;
  float ls0 = 0.f, ls1 = 0.f;
  const float c256 = 0.00390625f;

  // prefetch dist tile 0 (rows srow, +8, +16, +24)
  uint2 dr0 = *(const uint2*)&dist[doff];
  uint2 dr1 = *(const uint2*)&dist[doff + 8u*4096u];
  uint2 dr2 = *(const uint2*)&dist[doff + 16u*4096u];
  uint2 dr3 = *(const uint2*)&dist[doff + 24u*4096u];
  doff += 64;

  for (int tt = 0; tt < 8; tt++){
    // commit dist regs to LDS (wave-private, no barrier)
    *(uint2*)&dls[wv][     srow][scol] = dr0;
    *(uint2*)&dls[wv][ 8 + srow][scol] = dr1;
    *(uint2*)&dls[wv][16 + srow][scol] = dr2;
    *(uint2*)&dls[wv][24 + srow][scol] = dr3;
    if (tt != 7){
      dr0 = *(const uint2*)&dist[doff];
      dr1 = *(const uint2*)&dist[doff + 8u*4096u];
      dr2 = *(const uint2*)&dist[doff + 16u*4096u];
      dr3 = *(const uint2*)&dist[doff + 24u*4096u];
      doff += 64;
    }
    // per-fn: QK^T fragment then immediate softmax (short score live range)
    #pragma unroll
    for (int fn = 0; fn < 4; fn++){
      bf16x8 kf = *(const bf16x8*)&kg[koff + (u32)(fn * 16 * 512)];
      f32x4 s0 = __builtin_amdgcn_mfma_f32_16x16x32_bf16(kf, qf0, zero, 0, 0, 0);
      f32x4 s1 = __builtin_amdgcn_mfma_f32_16x16x32_bf16(kf, qf1, zero, 0, 0, 0);
      {
        u32 dw = *(const u32*)&dls[wv][row16][fn*16 + rg];
        u32 pb = __builtin_amdgcn_perm(B45, B0123, dw);
        float p0 = exp2f(fmaf((float)( pb        & 255u), c256, s0[0]));
        float p1 = exp2f(fmaf((float)((pb >>  8) & 255u), c256, s0[1]));
        float p2 = exp2f(fmaf((float)((pb >> 16) & 255u), c256, s0[2]));
        float p3 = exp2f(fmaf((float)( pb >> 24        ), c256, s0[3]));
        ls0 += (p0 + p1) + (p2 + p3);
        uint2 pw = { pk2(p0, p1), pk2(p2, p3) };
        *(uint2*)&P[wv][row16][fn*16 + rg] = pw;
      }
      {
        u32 dw = *(const u32*)&dls[wv][16 + row16][fn*16 + rg];
        u32 pb = __builtin_amdgcn_perm(B45, B0123, dw);
        float p0 = exp2f(fmaf((float)( pb        & 255u), c256, s1[0]));
        float p1 = exp2f(fmaf((float)((pb >>  8) & 255u), c256, s1[1]));
        float p2 = exp2f(fmaf((float)((pb >> 16) & 255u), c256, s1[2]));
        float p3 = exp2f(fmaf((float)( pb >> 24        ), c256, s1[3]));
        ls1 += (p0 + p1) + (p2 + p3);
        uint2 pw = { pk2(p0, p1), pk2(p2, p3) };
        *(uint2*)&P[wv][16 + row16][fn*16 + rg] = pw;
      }
    }
    koff += 64u * 512u;
    // PV: fd-outer to limit live operands
    #pragma unroll
    for (int ks = 0; ks < 2; ks++){
      bf16x8 pa0 = *(const bf16x8*)&P[wv][     row16][ks*32 + kq];
      bf16x8 pa1 = *(const bf16x8*)&P[wv][16 + row16][ks*32 + kq];
      {
        bf16x8 vf = *(const bf16x8*)&vtg[voff0 + (u32)(ks*32)];
        acc00 = __builtin_amdgcn_mfma_f32_16x16x32_bf16(pa0, vf, acc00, 0, 0, 0);
        acc10 = __builtin_amdgcn_mfma_f32_16x16x32_bf16(pa1, vf, acc10, 0, 0, 0);
      }
      {
        bf16x8 vf = *(const bf16x8*)&vtg[voff1 + (u32)(ks*32)];
        acc01 = __builtin_amdgcn_mfma_f32_16x16x32_bf16(pa0, vf, acc01, 0, 0, 0);
        acc11 = __builtin_amdgcn_mfma_f32_16x16x32_bf16(pa1, vf, acc11, 0, 0, 0);
      }
    }
    voff0 += 64; voff1 += 64;
  }
  // reduce l across the 4 lane-groups (disjoint k per group)
  ls0 += __shfl_xor(ls0, 16, 64);
  ls0 += __shfl_xor(ls0, 32, 64);
  ls1 += __shfl_xor(ls1, 16, 64);
  ls1 += __shfl_xor(ls1, 32, 64);
  // write partials (bf16)
  size_t base = ((size_t)ck * 8 + h) * 4096 + q0;
  #pragma unroll
  for (int r = 0; r < 4; r++){
    pacc[(base +      rg + r) * 32 +      row16] = f2b(acc00[r]);
    pacc[(base +      rg + r) * 32 + 16 + row16] = f2b(acc01[r]);
    pacc[(base + 16 + rg + r) * 32 +      row16] = f2b(acc10[r]);
    pacc[(base + 16 + rg + r) * 32 + 16 + row16] = f2b(acc11[r]);
  }
  if ((lane >> 4) == 0){
    pml[base +      row16] = ls0;
    pml[base + 16 + row16] = ls1;
  }
}

// ---------------- split-K merge: plain sums (fixed max) ----------------
__global__ __launch_bounds__(256) void k_merge(const u16* __restrict__ pacc,
                                               const float* __restrict__ pml,
                                               u16* __restrict__ attb){
  int row = blockIdx.x;
  int t = threadIdx.x;
  int h = t >> 5, col = t & 31;
  float o = 0.f, L = 0.f;
  #pragma unroll
  for (int c = 0; c < 8; c++){
    size_t base = ((size_t)c * 8 + h) * 4096 + row;
    o += b2f(pacc[base * 32 + col]);
    L += pml[base];
  }
  attb[(size_t)row * 256 + h * 32 + col] = f2b(o / L);
}

// ---------------- residual + LayerNorm (wave per row) ----------------
__global__ __launch_bounds__(256) void k_ln(const float* __restrict__ ina, const float* __restrict__ inb,
                                            const float* __restrict__ g, const float* __restrict__ b,
                                            float* __restrict__ outF, u16* __restrict__ outB){
  int t = threadIdx.x;
  int wv = t >> 6, lane = t & 63;
  int row = blockIdx.x * 4 + wv;
  size_t base = (size_t)row * CC + lane * 4;
  float4 xa = *(const float4*)&ina[base];
  float4 xb = *(const float4*)&inb[base];
  float v0 = xa.x + xb.x, v1 = xa.y + xb.y, v2 = xa.z + xb.z, v3 = xa.w + xb.w;
  float s  = v0 + v1 + v2 + v3;
  float s2 = v0*v0 + v1*v1 + v2*v2 + v3*v3;
  #pragma unroll
  for (int m = 1; m < 64; m <<= 1){
    s  += __shfl_xor(s,  m, 64);
    s2 += __shfl_xor(s2, m, 64);
  }
  float mu  = s * (1.0f / 256.0f);
  float var = s2 * (1.0f / 256.0f) - mu * mu;
  float rs  = rsqrtf(var + 1e-5f);
  float4 gv = *(const float4*)&g[lane * 4];
  float4 bv = *(const float4*)&b[lane * 4];
  float o0 = (v0 - mu) * rs * gv.x + bv.x;
  float o1 = (v1 - mu) * rs * gv.y + bv.y;
  float o2 = (v2 - mu) * rs * gv.z + bv.z;
  float o3 = (v3 - mu) * rs * gv.w + bv.w;
  if (outF){ float4 o = {o0, o1, o2, o3}; *(float4*)&outF[base] = o; }
  if (outB){
    outB[base+0] = f2b(o0); outB[base+1] = f2b(o1);
    outB[base+2] = f2b(o2); outB[base+3] = f2b(o3);
  }
}

// ---------------- launch ----------------
extern "C" void kernel_launch(void* const* d_in, const int* in_sizes, int n_in,
                              void* d_out, int out_size, void* d_ws, size_t ws_size,
                              hipStream_t stream){
  const float* x    = (const float*)d_in[0];
  const int*   ei   = (const int*)  d_in[1];
  const float* demb = (const float*)d_in[2];
  const float* spa  = (const float*)d_in[3];
  const float* Wq   = (const float*)d_in[4];
  const float* bq   = (const float*)d_in[5];
  const float* Wk   = (const float*)d_in[6];
  const float* bk   = (const float*)d_in[7];
  const float* Wv   = (const float*)d_in[8];
  const float* bv   = (const float*)d_in[9];
  const float* Wo   = (const float*)d_in[10];
  const float* bo   = (const float*)d_in[11];
  const float* g1   = (const float*)d_in[12];
  const float* b1   = (const float*)d_in[13];
  const float* g2   = (const float*)d_in[14];
  const float* b2   = (const float*)d_in[15];
  const float* Wf1  = (const float*)d_in[16];
  const float* bf1  = (const float*)d_in[17];
  const float* Wf2  = (const float*)d_in[18];
  const float* bf2  = (const float*)d_in[19];

  char* ws = (char*)d_ws;
  size_t off = 0;
  auto take = [&](size_t bytes)->char*{
    char* p = ws + off;
    off = (off + bytes + 255) & ~(size_t)255;
    return p;
  };
  int* deg    = (int*)take(4096 * 4);
  int* rowp   = (int*)take(4097 * 4);
  int* cur    = (int*)take(4096 * 4);
  int* col    = (int*)take(131072 * 4);
  u16* hid    = (u16*)take(2097152);
  u16* Wqkvt  = (u16*)take(768 * 256 * 2);
  u16* Wot    = (u16*)take(131072);
  u16* Wf1t   = (u16*)take(262144);
  u16* Wf2t   = (u16*)take(262144);
  float* bcat = (float*)take(768 * 4);
  u16* qkv    = (u16*)take(4194304);        // [4096][512] Q|K bf16 (Q pre-scaled)
  u16* vt     = (u16*)take(2097152);        // [256][4096] V transposed
  u16* attb   = (u16*)take(2097152);
  char* SC    = take(18 * 1048576);         // BFS / attn partials / post-attn scratch
  u8* dist    = (u8*)take(16777216);
  u64* B[5];
  for (int i = 0; i < 5; i++) B[i] = (u64*)(SC + (size_t)i * 2097152);
  u16*   pacc    = (u16*)SC;                         // 16 MB bf16 partials (B dead after k_dist)
  float* pml     = (float*)(SC + 16777216);          // 1 MB
  float* attnout = (float*)SC;                       // 4 MB (pacc dead after merge)
  float* hf      = (float*)(SC + 4194304);           // 4 MB
  u16*   hbf     = (u16*)  (SC + 8388608);           // 2 MB
  u16*   ff1     = (u16*)  dist;                     // 4 MB (dist dead after attn)
  float* ff2     = (float*)(dist + 8388608);         // 4 MB
  float* outp    = (float*)d_out;

  hipMemsetAsync(deg, 0, 4096 * 4, stream);
  k_deg   <<<256,  256, 0, stream>>>(ei, deg);
  k_scan  <<<1,    256, 0, stream>>>(deg, rowp, cur);
  k_fill  <<<256,  256, 0, stream>>>(ei, cur, col);
  k_hidden<<<4096, 256, 0, stream>>>(x, demb, deg, hid);
  k_b0    <<<1024, 256, 0, stream>>>(B[0]);
  for (int d = 0; d < 4; d++)
    k_prop<<<1024, 256, 0, stream>>>(B[d], B[d + 1], rowp, col);
  k_dist  <<<1024, 256, 0, stream>>>(B[1], B[2], B[3], B[4], dist);

  k_tconv<<<dim3(8, 8, 6), 256, 0, stream>>>(Wq, Wk, Wv, Wo, Wf1, Wf2,
                                             Wqkvt, Wqkvt + 256*256, Wqkvt + 512*256,
                                             Wot, Wf1t, Wf2t);
  k_bcat <<<3, 256, 0, stream>>>(bq, bk, bv, bcat);

  // fused QKV: N=768; cols [0,512) -> qkv row-major (Q pre-scaled), cols [512,768) -> vt transposed
  k_gemm32<<<dim3(128, 12), 256, 0, stream>>>(hid, Wqkvt, bcat, nullptr, qkv, vt,
                                              4096, 768, 256, 512, 2 | 16);

  k_attn <<<dim3(128, 2, 8), 256, 0, stream>>>(qkv, qkv + 256, vt, dist, spa, pacc, pml);
  k_merge<<<4096, 256, 0, stream>>>(pacc, pml, attb);

  k_gemm32<<<dim3(128, 4), 256, 0, stream>>>(attb, Wot, bo, attnout, nullptr, nullptr,
                                             4096, 256, 256, 256, 1);
  k_ln   <<<1024, 256, 0, stream>>>(x, attnout, g1, b1, hf, hbf);
  k_gemm32<<<dim3(128, 8), 256, 0, stream>>>(hbf, Wf1t, bf1, nullptr, ff1, nullptr,
                                             4096, 512, 256, 512, 2 | 8);
  k_gemm32<<<dim3(128, 4), 256, 0, stream>>>(ff1, Wf2t, bf2, ff2, nullptr, nullptr,
                                             4096, 256, 512, 256, 1);
  k_ln   <<<1024, 256, 0, stream>>>(hf, ff2, g2, b2, outp, nullptr);
}